// Round 2
// baseline (46.419 us; speedup 1.0000x reference)
//
#include <hip/hip_runtime.h>
#include <hip/hip_bf16.h>

#define BATCH    512
#define IN_WIDTH 4096
#define OUT_F    4096
#define FAN_IN   128
#define HALF_B   256   // batch split: inT stored as [2][IN_WIDTH][256] bf16

// ---------------------------------------------------------------------------
// Kernel A: transpose input [BATCH][IN_WIDTH] f32 -> inT [2][IN_WIDTH][256] bf16
// (batch-split so each half is a 2 MB L2-resident block during the gather)
// ---------------------------------------------------------------------------
__global__ __launch_bounds__(256) void k_transpose_in(const float* __restrict__ in,
                                                      uint16_t* __restrict__ inT) {
  __shared__ float tile[32][33];
  const int jt = blockIdx.x * 32;   // column (index-space) tile
  const int bt = blockIdx.y * 32;   // batch tile
  const int tx = threadIdx.x;       // 0..31
  const int ty = threadIdx.y;       // 0..7
#pragma unroll
  for (int r = 0; r < 32; r += 8) {
    tile[ty + r][tx] = in[(size_t)(bt + ty + r) * IN_WIDTH + (jt + tx)];
  }
  __syncthreads();
#pragma unroll
  for (int r = 0; r < 32; r += 8) {
    const int b = bt + tx;
    const int j = jt + ty + r;
    __hip_bfloat16 hv = __float2bfloat16(tile[tx][ty + r]);
    inT[((size_t)(b >> 8) * IN_WIDTH + j) * HALF_B + (b & 255)] =
        *reinterpret_cast<const uint16_t*>(&hv);
  }
}

// ---------------------------------------------------------------------------
// Kernel B: gather + FMA. One WAVE per (o, batch-half).
//   outT[o][h*256 + 4*lane .. +3] = bias[o] + sum_f inT[h][idx[o,f]][...] * w[o,f]
// idx/weight loads are wave-uniform (readfirstlane o) -> scalar loads.
// Each lane loads dwordx2 = 4 bf16 batches per f, coalesced 512 B per wave.
// ---------------------------------------------------------------------------
__global__ __launch_bounds__(256) void k_gather_fma(const uint16_t* __restrict__ inT,
                                                    const float* __restrict__ weight,
                                                    const float* __restrict__ bias,
                                                    const int* __restrict__ idx,
                                                    float* __restrict__ outT) {
  const int wave = threadIdx.x >> 6;  // 0..3
  const int lane = threadIdx.x & 63;
  const int o = __builtin_amdgcn_readfirstlane(blockIdx.x * 4 + wave);
  const int h = blockIdx.y;           // batch half (slow grid dim)

  const int*   __restrict__ idxo = idx + (size_t)o * FAN_IN;
  const float* __restrict__ wo   = weight + (size_t)o * FAN_IN;
  const uint16_t* __restrict__ base = inT + (size_t)h * IN_WIDTH * HALF_B + 4 * lane;

  float a0 = 0.f, a1 = 0.f, a2 = 0.f, a3 = 0.f;
#pragma unroll 8
  for (int f = 0; f < FAN_IN; ++f) {
    const int   j = idxo[f];          // s_load (wave-uniform)
    const float w = wo[f];            // s_load
    const uint2 v = *reinterpret_cast<const uint2*>(base + (size_t)j * HALF_B);
    a0 = fmaf(__uint_as_float(v.x << 16), w, a0);
    a1 = fmaf(__uint_as_float(v.x & 0xffff0000u), w, a1);
    a2 = fmaf(__uint_as_float(v.y << 16), w, a2);
    a3 = fmaf(__uint_as_float(v.y & 0xffff0000u), w, a3);
  }
  const float bz = bias[o];
  float4 r = make_float4(a0 + bz, a1 + bz, a2 + bz, a3 + bz);
  *reinterpret_cast<float4*>(outT + (size_t)o * BATCH + h * HALF_B + 4 * lane) = r;
}

// ---------------------------------------------------------------------------
// Kernel C: transpose outT [OUT_F][BATCH] f32 -> out [BATCH][OUT_F] f32
// ---------------------------------------------------------------------------
__global__ __launch_bounds__(256) void k_transpose_out(const float* __restrict__ outT,
                                                       float* __restrict__ out) {
  __shared__ float tile[32][33];
  const int ot = blockIdx.x * 32;
  const int bt = blockIdx.y * 32;
  const int tx = threadIdx.x;
  const int ty = threadIdx.y;
#pragma unroll
  for (int r = 0; r < 32; r += 8) {
    tile[ty + r][tx] = outT[(size_t)(ot + ty + r) * BATCH + (bt + tx)];
  }
  __syncthreads();
#pragma unroll
  for (int r = 0; r < 32; r += 8) {
    out[(size_t)(bt + ty + r) * OUT_F + (ot + tx)] = tile[tx][ty + r];
  }
}

extern "C" void kernel_launch(void* const* d_in, const int* in_sizes, int n_in,
                              void* d_out, int out_size, void* d_ws, size_t ws_size,
                              hipStream_t stream) {
  const float* input  = (const float*)d_in[0];   // [512][4096] f32
  const float* weight = (const float*)d_in[1];   // [4096][128] f32
  const float* bias   = (const float*)d_in[2];   // [4096]      f32
  const int*   idx    = (const int*)d_in[3];     // [4096][128] int32
  float* out = (float*)d_out;                    // [512][4096] f32

  // Workspace layout: inT (bf16, 4 MB) | outT (f32, 8 MB)
  uint16_t* inT = (uint16_t*)d_ws;
  float* outT = (float*)((char*)d_ws + (size_t)IN_WIDTH * BATCH * sizeof(uint16_t));

  dim3 tblk(32, 8);
  k_transpose_in<<<dim3(IN_WIDTH / 32, BATCH / 32), tblk, 0, stream>>>(input, inT);
  k_gather_fma<<<dim3(OUT_F / 4, 2), dim3(256), 0, stream>>>(inT, weight, bias, idx, outT);
  k_transpose_out<<<dim3(OUT_F / 32, BATCH / 32), tblk, 0, stream>>>(outT, out);
}

// Round 3
// 42.824 us; speedup vs baseline: 1.0840x; 1.0840x over previous
//
#include <hip/hip_runtime.h>
#include <hip/hip_bf16.h>

#define BATCH    512
#define IN_WIDTH 4096
#define OUT_F    4096
#define FAN_IN   128
#define BCHUNK   16                 // batches per LDS-resident slice
#define NBG      (BATCH / BCHUNK)   // 32
#define OBLK     512                // o-range per gather block
#define NOG      (OUT_F / OBLK)     // 8

// ---------------------------------------------------------------------------
// Kernel A: input[b][j] f32 -> inTg[bg][j][16] bf16  (chunk-major so the
// gather kernel's 128 KB LDS stage is one contiguous coalesced read)
// ---------------------------------------------------------------------------
__global__ __launch_bounds__(256) void k_transpose_in(const float* __restrict__ in,
                                                      uint16_t* __restrict__ inTg) {
  __shared__ float tile[32][33];
  const int jt = blockIdx.x * 32;   // index-space tile
  const int bt = blockIdx.y * 32;   // batch tile
  const int tx = threadIdx.x;       // 0..31
  const int ty = threadIdx.y;       // 0..7
#pragma unroll
  for (int r = 0; r < 32; r += 8) {
    tile[ty + r][tx] = in[(size_t)(bt + ty + r) * IN_WIDTH + (jt + tx)];
  }
  __syncthreads();
#pragma unroll
  for (int r = 0; r < 32; r += 8) {
    const int b = bt + tx;
    const int j = jt + ty + r;
    __hip_bfloat16 hv = __float2bfloat16(tile[tx][ty + r]);
    inTg[((size_t)(b >> 4) * IN_WIDTH + j) * BCHUNK + (b & 15)] =
        *reinterpret_cast<const uint16_t*>(&hv);
  }
}

// ---------------------------------------------------------------------------
// Kernel P: pack idx+weight -> pk[o][f] = {j, bits(w)}  (one dwordx4 = 2 f)
// ---------------------------------------------------------------------------
__global__ __launch_bounds__(256) void k_pack(const int* __restrict__ idx,
                                              const float* __restrict__ weight,
                                              uint2* __restrict__ pk) {
  const int i = blockIdx.x * 256 + threadIdx.x;
  uint2 e;
  e.x = (uint32_t)idx[i];
  e.y = __float_as_uint(weight[i]);
  pk[i] = e;
}

// ---------------------------------------------------------------------------
// Kernel B: LDS-staged gather + FMA.
// Block (og, bg): stage inTg[bg] (4096 rows x 16 batches bf16 = 128 KB) into
// LDS, then each lane owns (o, 8 batches): 128 ds_read_b128 row gathers.
//   outT[o][bg*16 + p*8 + i] = bias[o] + sum_f inS[j_f][p*8+i] * w_f
// ---------------------------------------------------------------------------
__global__ __launch_bounds__(1024, 1) void k_gather_lds(const uint16_t* __restrict__ inTg,
                                                        const uint2* __restrict__ pk,
                                                        const float* __restrict__ bias,
                                                        float* __restrict__ outT) {
  extern __shared__ uint16_t inS[];   // [IN_WIDTH][BCHUNK] bf16, rows 32 B
  const int og = blockIdx.x;
  const int bg = blockIdx.y;
  const int t  = threadIdx.x;

  // ---- stage 128 KB, contiguous ----
  {
    const uint4* __restrict__ src =
        reinterpret_cast<const uint4*>(inTg + (size_t)bg * IN_WIDTH * BCHUNK);
    uint4* dst = reinterpret_cast<uint4*>(inS);
#pragma unroll
    for (int i = 0; i < 8; ++i) {
      dst[i * 1024 + t] = src[i * 1024 + t];
    }
  }
  __syncthreads();

  const int wv = t >> 6;
  const int l  = t & 63;
  const int o  = og * OBLK + wv * 32 + (l >> 1);  // 32 o per wave, 2 lanes/o
  const int p  = l & 1;                           // batch half within row

  const uint4* __restrict__ pko = reinterpret_cast<const uint4*>(pk + (size_t)o * FAN_IN);
  const char* rowbase = reinterpret_cast<const char*>(inS) + p * 16;

  float a0 = 0.f, a1 = 0.f, a2 = 0.f, a3 = 0.f;
  float a4 = 0.f, a5 = 0.f, a6 = 0.f, a7 = 0.f;

#pragma unroll 2
  for (int f2 = 0; f2 < FAN_IN / 2; ++f2) {
    const uint4 q = pko[f2];   // {j0, w0, j1, w1}
    {
      const uint4 v = *reinterpret_cast<const uint4*>(rowbase + q.x * 32);
      const float w = __uint_as_float(q.y);
      a0 = fmaf(__uint_as_float(v.x << 16),          w, a0);
      a1 = fmaf(__uint_as_float(v.x & 0xffff0000u),  w, a1);
      a2 = fmaf(__uint_as_float(v.y << 16),          w, a2);
      a3 = fmaf(__uint_as_float(v.y & 0xffff0000u),  w, a3);
      a4 = fmaf(__uint_as_float(v.z << 16),          w, a4);
      a5 = fmaf(__uint_as_float(v.z & 0xffff0000u),  w, a5);
      a6 = fmaf(__uint_as_float(v.w << 16),          w, a6);
      a7 = fmaf(__uint_as_float(v.w & 0xffff0000u),  w, a7);
    }
    {
      const uint4 v = *reinterpret_cast<const uint4*>(rowbase + q.z * 32);
      const float w = __uint_as_float(q.w);
      a0 = fmaf(__uint_as_float(v.x << 16),          w, a0);
      a1 = fmaf(__uint_as_float(v.x & 0xffff0000u),  w, a1);
      a2 = fmaf(__uint_as_float(v.y << 16),          w, a2);
      a3 = fmaf(__uint_as_float(v.y & 0xffff0000u),  w, a3);
      a4 = fmaf(__uint_as_float(v.z << 16),          w, a4);
      a5 = fmaf(__uint_as_float(v.z & 0xffff0000u),  w, a5);
      a6 = fmaf(__uint_as_float(v.w << 16),          w, a6);
      a7 = fmaf(__uint_as_float(v.w & 0xffff0000u),  w, a7);
    }
  }

  const float bz = bias[o];
  float4 r0 = make_float4(a0 + bz, a1 + bz, a2 + bz, a3 + bz);
  float4 r1 = make_float4(a4 + bz, a5 + bz, a6 + bz, a7 + bz);
  float4* dst = reinterpret_cast<float4*>(outT + (size_t)o * BATCH + bg * BCHUNK + p * 8);
  dst[0] = r0;
  dst[1] = r1;
}

// ---------------------------------------------------------------------------
// Kernel C: transpose outT [OUT_F][BATCH] f32 -> out [BATCH][OUT_F] f32
// ---------------------------------------------------------------------------
__global__ __launch_bounds__(256) void k_transpose_out(const float* __restrict__ outT,
                                                       float* __restrict__ out) {
  __shared__ float tile[32][33];
  const int ot = blockIdx.x * 32;
  const int bt = blockIdx.y * 32;
  const int tx = threadIdx.x;
  const int ty = threadIdx.y;
#pragma unroll
  for (int r = 0; r < 32; r += 8) {
    tile[ty + r][tx] = outT[(size_t)(ot + ty + r) * BATCH + (bt + tx)];
  }
  __syncthreads();
#pragma unroll
  for (int r = 0; r < 32; r += 8) {
    out[(size_t)(bt + ty + r) * OUT_F + (ot + tx)] = tile[tx][ty + r];
  }
}

extern "C" void kernel_launch(void* const* d_in, const int* in_sizes, int n_in,
                              void* d_out, int out_size, void* d_ws, size_t ws_size,
                              hipStream_t stream) {
  const float* input  = (const float*)d_in[0];   // [512][4096] f32
  const float* weight = (const float*)d_in[1];   // [4096][128] f32
  const float* bias   = (const float*)d_in[2];   // [4096]      f32
  const int*   idx    = (const int*)d_in[3];     // [4096][128] int32
  float* out = (float*)d_out;                    // [512][4096] f32

  // ws layout: inTg (bf16, 4 MB) | outT (f32, 8 MB) | pk (uint2, 4 MB)
  uint16_t* inTg = (uint16_t*)d_ws;
  float*    outT = (float*)((char*)d_ws + 4u * 1024 * 1024);
  uint2*    pk   = (uint2*)((char*)d_ws + 12u * 1024 * 1024);

  dim3 tblk(32, 8);
  k_transpose_in<<<dim3(IN_WIDTH / 32, BATCH / 32), tblk, 0, stream>>>(input, inTg);
  k_pack<<<dim3(OUT_F * FAN_IN / 256), dim3(256), 0, stream>>>(idx, weight, pk);
  k_gather_lds<<<dim3(NOG, NBG), dim3(1024), IN_WIDTH * BCHUNK * sizeof(uint16_t), stream>>>(
      inTg, pk, bias, outT);
  k_transpose_out<<<dim3(OUT_F / 32, BATCH / 32), tblk, 0, stream>>>(outT, out);
}